// Round 1
// baseline (610.143 us; speedup 1.0000x reference)
//
#include <hip/hip_runtime.h>

namespace {

constexpr int Bn = 4, Cn = 3, Hn = 1080, Wn = 1920;
constexpr int HW = Hn * Wn;
constexpr int Gt = Wn / 4;   // 480 aligned 4-texel groups per row
constexpr int Wt = Wn / 4;   // legacy tile-cols (old path)
constexpr int Ht = Hn / 4;   // legacy tile-rows (old path)
constexpr float kAlpha = 0.1f;
constexpr float kInv2047 = 1.0f / 2047.0f;
constexpr float kInv1023 = 1.0f / 1023.0f;

typedef float v2f __attribute__((ext_vector_type(2)));
typedef float v4f __attribute__((ext_vector_type(4)));
typedef unsigned int v4u __attribute__((ext_vector_type(4)));

__device__ inline unsigned quant_rgb(float r, float g, float b)
{
    const unsigned R  = (unsigned)(fminf(fmaxf(r, 0.0f), 1.0f) * 2047.0f + 0.5f);
    const unsigned G  = (unsigned)(fminf(fmaxf(g, 0.0f), 1.0f) * 2047.0f + 0.5f);
    const unsigned Bq = (unsigned)(fminf(fmaxf(b, 0.0f), 1.0f) * 1023.0f + 0.5f);
    return (R << 21) | (G << 10) | Bq;
}

// ================== NEW PATH: 4-phase x-shifted packed texture =============
// phase k (k=0..3), batch b, stored_k[y][x'] = quant(hist[b][y][min(x'+k, Wn-1)])
// layout: packed[((b*4 + k)*HW) + y*Wn + x']   (plain row-major per phase)
// Gather window [W0..W0+3] with k=W0&3, g=W0>>2 is ONE aligned dwordx4 per row.
__global__ __launch_bounds__(256)
void pack_phased(const float* __restrict__ hist, unsigned int* __restrict__ packed)
{
    const int tid = blockIdx.x * 256 + threadIdx.x;   // Bn*Hn*Gt = 2,073,600
    const int g   = tid % Gt;
    const int rem = tid / Gt;
    const int y   = rem % Hn;
    const int b   = rem / Hn;
    const int x0  = g * 4;

    const float* base = hist + (size_t)b * Cn * HW + (size_t)y * Wn + x0;
    const v4f r  = *(const v4f*)(base);
    const v4f gr = *(const v4f*)(base + HW);
    const v4f bl = *(const v4f*)(base + 2 * HW);

    const unsigned q0 = quant_rgb(r.x, gr.x, bl.x);
    const unsigned q1 = quant_rgb(r.y, gr.y, bl.y);
    const unsigned q2 = quant_rgb(r.z, gr.z, bl.z);
    const unsigned q3 = quant_rgb(r.w, gr.w, bl.w);

    // neighbor-group texels x0+4..x0+6 via wave shuffle (lanes are g-adjacent)
    unsigned n0 = __shfl_down(q0, 1);
    unsigned n1 = __shfl_down(q1, 1);
    unsigned n2 = __shfl_down(q2, 1);
    const int lane = threadIdx.x & 63;
    if (lane == 63 && g < Gt - 1) {        // wave edge: fetch directly (in-row)
        n0 = quant_rgb(base[4], base[4 + HW], base[4 + 2 * HW]);
        n1 = quant_rgb(base[5], base[5 + HW], base[5 + 2 * HW]);
        n2 = quant_rgb(base[6], base[6 + HW], base[6 + 2 * HW]);
    }
    if (g == Gt - 1) { n0 = q3; n1 = q3; n2 = q3; }  // right-edge clamp pad

    unsigned int* dst = packed + (size_t)b * 4 * HW + (size_t)y * Wn + x0;
    *(v4u*)(dst)          = (v4u){q0, q1, q2, q3};
    *(v4u*)(dst + HW)     = (v4u){q1, q2, q3, n0};
    *(v4u*)(dst + 2 * HW) = (v4u){q2, q3, n0, n1};
    *(v4u*)(dst + 3 * HW) = (v4u){q3, n0, n1, n2};
}

// one pixel's 5-tap bicubic: exactly 4 aligned dwordx4 loads, branch-free extract
__device__ inline void bicubic_gather4(const unsigned int* __restrict__ pp,
                                       float gx, float gy, float rep[3])
{
    const float posx = (gx + 1.0f) * 0.5f * (float)Wn;
    const float posy = (gy + 1.0f) * 0.5f * (float)Hn;
    const float Xf = floorf(posx - 0.5f);
    const float Yf = floorf(posy - 0.5f);
    const float fx = posx - (Xf + 0.5f);
    const float fy = posy - (Yf + 0.5f);

    const float fx2 = fx * fx, fx3 = fx2 * fx;
    const float w0x = -0.5f * fx3 + fx2 - 0.5f * fx;
    const float w1x =  1.5f * fx3 - 2.5f * fx2 + 1.0f;
    const float w2x = -1.5f * fx3 + 2.0f * fx2 + 0.5f * fx;
    const float w3x =  0.5f * fx3 - 0.5f * fx2;
    const float w12x = w1x + w2x;
    const float bxr  = w2x / w12x;

    const float fy2 = fy * fy, fy3 = fy2 * fy;
    const float w0y = -0.5f * fy3 + fy2 - 0.5f * fy;
    const float w1y =  1.5f * fy3 - 2.5f * fy2 + 1.0f;
    const float w2y = -1.5f * fy3 + 2.0f * fy2 + 0.5f * fy;
    const float w3y =  0.5f * fy3 - 0.5f * fy2;
    const float w12y = w1y + w2y;
    const float byr  = w2y / w12y;

    const int X = (int)Xf;
    const int Y = (int)Yf;

    const float vxm1 = ((unsigned)(X - 1) < (unsigned)Wn) ? 1.0f : 0.0f;
    const float vx0  = ((unsigned)(X    ) < (unsigned)Wn) ? 1.0f : 0.0f;
    const float vx1  = ((unsigned)(X + 1) < (unsigned)Wn) ? 1.0f : 0.0f;
    const float vx2  = ((unsigned)(X + 2) < (unsigned)Wn) ? 1.0f : 0.0f;
    const float vym1 = ((unsigned)(Y - 1) < (unsigned)Hn) ? 1.0f : 0.0f;
    const float vy0  = ((unsigned)(Y    ) < (unsigned)Hn) ? 1.0f : 0.0f;
    const float vy1  = ((unsigned)(Y + 1) < (unsigned)Hn) ? 1.0f : 0.0f;
    const float vy2  = ((unsigned)(Y + 2) < (unsigned)Hn) ? 1.0f : 0.0f;

    const float k1 = w12x * w0y;
    const float k2 = w0x * w12y;
    const float k3 = w3x * w12y;
    const float k4 = w12x * w3y;
    const float k5 = w12x * w12y;
    const float inv_denom = 1.0f / (k1 + k2 + k3 + k4 + k5);

    const float wxl = 1.0f - bxr, wxh = bxr;
    const float wyl = 1.0f - byr, wyh = byr;

    const float wA = k1 * wxl * (vym1 * vx0);
    const float wB = k1 * wxh * (vym1 * vx1);
    const float wC = k2 * wyl * (vxm1 * vy0);
    const float wD = k2 * wyh * (vxm1 * vy1);
    const float wE = k3 * wyl * (vx2 * vy0);
    const float wF = k3 * wyh * (vx2 * vy1);
    const float wG = k4 * wxl * (vy2 * vx0);
    const float wH = k4 * wxh * (vy2 * vx1);
    const float wI = k5 * wxl * wyl * (vx0 * vy0);
    const float wJ = k5 * wxh * wyl * (vx1 * vy0);
    const float wK = k5 * wxl * wyh * (vx0 * vy1);
    const float wL = k5 * wxh * wyh * (vx1 * vy1);

    const int W0 = X - 1;                       // window = cols W0..W0+3
    const int k  = W0 & 3;                      // phase
    const int gq = min(max(W0 >> 2, 0), Gt - 1);

    const int rYm = min(max(Y - 1, 0), Hn - 1) * Wn;
    const int rY0 = min(max(Y,     0), Hn - 1) * Wn;
    const int rY1 = min(max(Y + 1, 0), Hn - 1) * Wn;
    const int rY2 = min(max(Y + 2, 0), Hn - 1) * Wn;

    const unsigned int* bk = pp + (size_t)k * HW + gq * 4;
    v4u R0 = *(const v4u*)(bk + rY0);
    v4u R1 = *(const v4u*)(bk + rY1);
    v4u Rm = *(const v4u*)(bk + rYm);
    v4u R2 = *(const v4u*)(bk + rY2);

    // exact-left-edge (W0 in [-3,-1]): misaligned partial window — rare; never
    // taken for mv in [0,1). Rebuild from phase-0 (= unshifted) with clamps.
    if (__builtin_expect(W0 < 0 && W0 > -4, 0)) {
        const int c0 = min(max(W0,     0), Wn - 1);
        const int c1 = min(max(W0 + 1, 0), Wn - 1);
        const int c2 = min(max(W0 + 2, 0), Wn - 1);
        const int c3 = min(max(W0 + 3, 0), Wn - 1);
        R0 = (v4u){pp[rY0 + c0], pp[rY0 + c1], pp[rY0 + c2], pp[rY0 + c3]};
        R1 = (v4u){pp[rY1 + c0], pp[rY1 + c1], pp[rY1 + c2], pp[rY1 + c3]};
        Rm = (v4u){pp[rYm + c0], pp[rYm + c1], pp[rYm + c2], pp[rYm + c3]};
        R2 = (v4u){pp[rY2 + c0], pp[rY2 + c1], pp[rY2 + c2], pp[rY2 + c3]};
    }

    float accR = 0.0f, accG = 0.0f, accB = 0.0f;
#define TAA_TAP(w_, t_) {                                                   \
    accR = fmaf(w_, (float)((t_) >> 21),           accR);                   \
    accG = fmaf(w_, (float)(((t_) >> 10) & 2047u), accG);                   \
    accB = fmaf(w_, (float)((t_) & 1023u),         accB); }
    // same accumulation order as before (A..L) for bit-stable results
    TAA_TAP(wA, Rm.y) TAA_TAP(wB, Rm.z) TAA_TAP(wC, R0.x) TAA_TAP(wD, R1.x)
    TAA_TAP(wE, R0.w) TAA_TAP(wF, R1.w) TAA_TAP(wG, R2.y) TAA_TAP(wH, R2.z)
    TAA_TAP(wI, R0.y) TAA_TAP(wJ, R0.z) TAA_TAP(wK, R1.y) TAA_TAP(wL, R1.z)
#undef TAA_TAP
    rep[0] = accR * (kInv2047 * inv_denom);
    rep[1] = accG * (kInv2047 * inv_denom);
    rep[2] = accB * (kInv1023 * inv_denom);
}

// ---- main TAA kernel (phased texture): 2 adjacent pixels per thread ----
__global__ __launch_bounds__(128)
void taa_main4(const float* __restrict__ xin,
               const v2f* __restrict__ mv,
               const unsigned int* __restrict__ packed,
               float* __restrict__ out)
{
    // batch = bid & 3: round-robin block->XCD pins batch b to XCDs {b,b+4}.
    const int bid = blockIdx.x;            // 32400 blocks
    const int b   = bid & 3;
    const int r   = bid >> 2;              // 0..8099
    const int u   = r * 128 + threadIdx.x; // 2px-unit
    const int py  = u / 960;
    const int P   = (u - py * 960) * 2;    // even pixel
    const int p   = py * Wn + P;

    const v4f gg = __builtin_nontemporal_load((const v4f*)&mv[(size_t)b * HW + p]);

    const unsigned int* __restrict__ pp = packed + (size_t)b * 4 * HW;
    float rep0[3], rep1[3];
    bicubic_gather4(pp, gg.x, gg.y, rep0);
    bicubic_gather4(pp, gg.z, gg.w, rep1);

    // ---- 3x3 pool: float2 column loads + wave shuffles ----
    const int pym = max(py - 1, 0) * Wn;
    const int py0 = py * Wn;
    const int pyp = min(py + 1, Hn - 1) * Wn;
    const int lane = threadIdx.x & 63;

    float ctr0[3], ctr1[3];
    float mxlo[3], mxhi[3], mnlo[3], mnhi[3];
    #pragma unroll
    for (int c = 0; c < Cn; ++c) {
        const float* __restrict__ xp = xin + (size_t)(b * Cn + c) * HW;
        const v2f a = *(const v2f*)(xp + pym + P);
        const v2f m = *(const v2f*)(xp + py0 + P);
        const v2f z = *(const v2f*)(xp + pyp + P);
        ctr0[c] = m.x; ctr1[c] = m.y;
        mxlo[c] = fmaxf(fmaxf(a.x, m.x), z.x);
        mxhi[c] = fmaxf(fmaxf(a.y, m.y), z.y);
        mnlo[c] = fminf(fminf(a.x, m.x), z.x);
        mnhi[c] = fminf(fminf(a.y, m.y), z.y);
    }

    float lmx[3], lmn[3], rmx[3], rmn[3];   // left = col P-1, right = col P+2
    #pragma unroll
    for (int c = 0; c < Cn; ++c) {
        lmx[c] = __shfl_up(mxhi[c], 1);
        lmn[c] = __shfl_up(mnhi[c], 1);
        rmx[c] = __shfl_down(mxlo[c], 1);
        rmn[c] = __shfl_down(mnlo[c], 1);
    }

    if (lane == 0 || lane == 63) {
        const int ex = (lane == 0) ? max(P - 1, 0) : min(P + 2, Wn - 1);
        #pragma unroll
        for (int c = 0; c < Cn; ++c) {
            const float* __restrict__ xp = xin + (size_t)(b * Cn + c) * HW;
            const float e0 = xp[pym + ex];
            const float e1 = xp[py0 + ex];
            const float e2 = xp[pyp + ex];
            const float emax = fmaxf(fmaxf(e0, e1), e2);
            const float emin = fminf(fminf(e0, e1), e2);
            if (lane == 0) { lmx[c] = emax; lmn[c] = emin; }
            else           { rmx[c] = emax; rmn[c] = emin; }
        }
    }

    #pragma unroll
    for (int c = 0; c < Cn; ++c) {
        const float mx0 = fmaxf(fmaxf(lmx[c], mxlo[c]), mxhi[c]);
        const float mn0 = fminf(fminf(lmn[c], mnlo[c]), mnhi[c]);
        const float mx1 = fmaxf(fmaxf(mxlo[c], mxhi[c]), rmx[c]);
        const float mn1 = fminf(fminf(mnlo[c], mnhi[c]), rmn[c]);

        float rv0 = fminf(fmaxf(rep0[c], 0.0f), 1.0f);
        float rv1 = fminf(fmaxf(rep1[c], 0.0f), 1.0f);
        rv0 = fminf(fmaxf(rv0, mn0), mx0);
        rv1 = fminf(fmaxf(rv1, mn1), mx1);

        v2f o;
        o.x = kAlpha * ctr0[c] + (1.0f - kAlpha) * rv0;
        o.y = kAlpha * ctr1[c] + (1.0f - kAlpha) * rv1;
        __builtin_nontemporal_store(o, (v2f*)&out[(size_t)(b * Cn + c) * HW + p]);
    }
}

// ================== OLD PATH (ws >= 33MB but < 133MB): tiled texture =======
__global__ __launch_bounds__(128)
void pack_tiled(const float* __restrict__ hist, unsigned int* __restrict__ packed)
{
    const int bid = blockIdx.x;            // Bn * Ht * 15
    const int b   = bid / (Ht * 15);
    const int r2  = bid - b * (Ht * 15);
    const int ty  = r2 / 15;
    const int txg = r2 - ty * 15;
    const int l   = threadIdx.x;
    const int tx  = txg * 32 + (l & 31);
    const int y   = ty * 4 + (l >> 5);
    const int x0  = tx * 4;

    const float* base = hist + (size_t)b * Cn * HW + (size_t)y * Wn + x0;
    const v4f r  = *(const v4f*)(base);
    const v4f g  = *(const v4f*)(base + HW);
    const v4f bl = *(const v4f*)(base + 2 * HW);

    v4u t;
    #pragma unroll
    for (int i = 0; i < 4; ++i)
        t[i] = quant_rgb(r[i], g[i], bl[i]);
    unsigned int* dst = packed + (size_t)b * HW + ((size_t)ty * Wt + tx) * 16 + (y & 3) * 4;
    *(v4u*)dst = t;
}

__device__ inline unsigned sel4(unsigned a, unsigned b, unsigned c, unsigned d, int s)
{
    const unsigned lo = (s & 1) ? b : a;
    const unsigned hi = (s & 1) ? d : c;
    return (s & 2) ? hi : lo;
}

__device__ inline void bicubic_gather(const unsigned int* __restrict__ pp,
                                      float gx, float gy, float rep[3])
{
    const float posx = (gx + 1.0f) * 0.5f * (float)Wn;
    const float posy = (gy + 1.0f) * 0.5f * (float)Hn;
    const float Xf = floorf(posx - 0.5f);
    const float Yf = floorf(posy - 0.5f);
    const float fx = posx - (Xf + 0.5f);
    const float fy = posy - (Yf + 0.5f);

    const float fx2 = fx * fx, fx3 = fx2 * fx;
    const float w0x = -0.5f * fx3 + fx2 - 0.5f * fx;
    const float w1x =  1.5f * fx3 - 2.5f * fx2 + 1.0f;
    const float w2x = -1.5f * fx3 + 2.0f * fx2 + 0.5f * fx;
    const float w3x =  0.5f * fx3 - 0.5f * fx2;
    const float w12x = w1x + w2x;
    const float bxr  = w2x / w12x;

    const float fy2 = fy * fy, fy3 = fy2 * fy;
    const float w0y = -0.5f * fy3 + fy2 - 0.5f * fy;
    const float w1y =  1.5f * fy3 - 2.5f * fy2 + 1.0f;
    const float w2y = -1.5f * fy3 + 2.0f * fy2 + 0.5f * fy;
    const float w3y =  0.5f * fy3 - 0.5f * fy2;
    const float w12y = w1y + w2y;
    const float byr  = w2y / w12y;

    const int X = (int)Xf;
    const int Y = (int)Yf;

    const float vxm1 = ((unsigned)(X - 1) < (unsigned)Wn) ? 1.0f : 0.0f;
    const float vx0  = ((unsigned)(X    ) < (unsigned)Wn) ? 1.0f : 0.0f;
    const float vx1  = ((unsigned)(X + 1) < (unsigned)Wn) ? 1.0f : 0.0f;
    const float vx2  = ((unsigned)(X + 2) < (unsigned)Wn) ? 1.0f : 0.0f;
    const float vym1 = ((unsigned)(Y - 1) < (unsigned)Hn) ? 1.0f : 0.0f;
    const float vy0  = ((unsigned)(Y    ) < (unsigned)Hn) ? 1.0f : 0.0f;
    const float vy1  = ((unsigned)(Y + 1) < (unsigned)Hn) ? 1.0f : 0.0f;
    const float vy2  = ((unsigned)(Y + 2) < (unsigned)Hn) ? 1.0f : 0.0f;

    const float k1 = w12x * w0y;
    const float k2 = w0x * w12y;
    const float k3 = w3x * w12y;
    const float k4 = w12x * w3y;
    const float k5 = w12x * w12y;
    const float inv_denom = 1.0f / (k1 + k2 + k3 + k4 + k5);

    const float wxl = 1.0f - bxr, wxh = bxr;
    const float wyl = 1.0f - byr, wyh = byr;

    const float wA = k1 * wxl * (vym1 * vx0);
    const float wB = k1 * wxh * (vym1 * vx1);
    const float wC = k2 * wyl * (vxm1 * vy0);
    const float wD = k2 * wyh * (vxm1 * vy1);
    const float wE = k3 * wyl * (vx2 * vy0);
    const float wF = k3 * wyh * (vx2 * vy1);
    const float wG = k4 * wxl * (vy2 * vx0);
    const float wH = k4 * wxh * (vy2 * vx1);
    const float wI = k5 * wxl * wyl * (vx0 * vy0);
    const float wJ = k5 * wxh * wyl * (vx1 * vy0);
    const float wK = k5 * wxl * wyh * (vx0 * vy1);
    const float wL = k5 * wxh * wyh * (vx1 * vy1);

    const int rYm = min(max(Y - 1, 0), Hn - 1);
    const int rY0 = min(max(Y,     0), Hn - 1);
    const int rY1 = min(max(Y + 1, 0), Hn - 1);
    const int rY2 = min(max(Y + 2, 0), Hn - 1);
    const int cX  = min(max(X,     0), Wn - 1);
    const int cX1 = min(max(X + 1, 0), Wn - 1);
    const int tx0 = min(max((X - 1) >> 2, 0), Wt - 1);
    const int tx1 = min(max((X + 2) >> 2, 0), Wt - 1);
    const int s1  = (X - 1) & 3;

    #define ROWBASE(rc, tx) ((((rc) >> 2) * Wt + (tx)) * 16 + ((rc) & 3) * 4)
    const v4u A0 = *(const v4u*)(pp + ROWBASE(rY0, tx0));
    const v4u A1 = *(const v4u*)(pp + ROWBASE(rY1, tx0));
    v4u B0 = {0, 0, 0, 0}, B1 = {0, 0, 0, 0};
    if (s1 != 0) {
        B0 = *(const v4u*)(pp + ROWBASE(rY0, tx1));
        B1 = *(const v4u*)(pp + ROWBASE(rY1, tx1));
    }
    const int txA = cX >> 2;
    const int sA  = cX & 3;
    const int sB  = cX1 & 3;
    const bool nb = (cX1 >> 2) != txA;
    const v4u Tm = *(const v4u*)(pp + ROWBASE(rYm, txA));
    const v4u T2 = *(const v4u*)(pp + ROWBASE(rY2, txA));
    unsigned um = 0, u2 = 0;
    if (nb) {
        um = pp[ROWBASE(rYm, txA + 1)];
        u2 = pp[ROWBASE(rY2, txA + 1)];
    }
    #undef ROWBASE

    const unsigned tA = sel4(Tm.x, Tm.y, Tm.z, Tm.w, sA);
    const unsigned tG = sel4(T2.x, T2.y, T2.z, T2.w, sA);
    const unsigned tB = nb ? um : sel4(Tm.x, Tm.y, Tm.z, Tm.w, sB);
    const unsigned tH = nb ? u2 : sel4(T2.x, T2.y, T2.z, T2.w, sB);

    const unsigned tC = sel4(A0.x, A0.y, A0.z, A0.w, s1);
    const unsigned tI = sel4(A0.y, A0.z, A0.w, B0.x, s1);
    const unsigned tJ = sel4(A0.z, A0.w, B0.x, B0.y, s1);
    const unsigned tE = sel4(A0.w, B0.x, B0.y, B0.z, s1);
    const unsigned tD = sel4(A1.x, A1.y, A1.z, A1.w, s1);
    const unsigned tK = sel4(A1.y, A1.z, A1.w, B1.x, s1);
    const unsigned tL = sel4(A1.z, A1.w, B1.x, B1.y, s1);
    const unsigned tF = sel4(A1.w, B1.x, B1.y, B1.z, s1);

    float accR = 0.0f, accG = 0.0f, accB = 0.0f;
#define TAA_TAP(w_, t_) {                                                   \
    accR = fmaf(w_, (float)((t_) >> 21),           accR);                   \
    accG = fmaf(w_, (float)(((t_) >> 10) & 2047u), accG);                   \
    accB = fmaf(w_, (float)((t_) & 1023u),         accB); }
    TAA_TAP(wA, tA) TAA_TAP(wB, tB) TAA_TAP(wC, tC) TAA_TAP(wD, tD)
    TAA_TAP(wE, tE) TAA_TAP(wF, tF) TAA_TAP(wG, tG) TAA_TAP(wH, tH)
    TAA_TAP(wI, tI) TAA_TAP(wJ, tJ) TAA_TAP(wK, tK) TAA_TAP(wL, tL)
#undef TAA_TAP
    rep[0] = accR * (kInv2047 * inv_denom);
    rep[1] = accG * (kInv2047 * inv_denom);
    rep[2] = accB * (kInv1023 * inv_denom);
}

__global__ __launch_bounds__(128)
void taa_main2(const float* __restrict__ xin,
               const v2f* __restrict__ mv,
               const unsigned int* __restrict__ packed,
               float* __restrict__ out)
{
    const int bid = blockIdx.x;            // 32400 blocks
    const int b   = bid & 3;
    const int r   = bid >> 2;
    const int u   = r * 128 + threadIdx.x;
    const int py  = u / 960;
    const int P   = (u - py * 960) * 2;
    const int p   = py * Wn + P;

    const v4f gg = __builtin_nontemporal_load((const v4f*)&mv[(size_t)b * HW + p]);

    const unsigned int* __restrict__ pp = packed + (size_t)b * HW;
    float rep0[3], rep1[3];
    bicubic_gather(pp, gg.x, gg.y, rep0);
    bicubic_gather(pp, gg.z, gg.w, rep1);

    const int pym = max(py - 1, 0) * Wn;
    const int py0 = py * Wn;
    const int pyp = min(py + 1, Hn - 1) * Wn;
    const int lane = threadIdx.x & 63;

    float ctr0[3], ctr1[3];
    float mxlo[3], mxhi[3], mnlo[3], mnhi[3];
    #pragma unroll
    for (int c = 0; c < Cn; ++c) {
        const float* __restrict__ xp = xin + (size_t)(b * Cn + c) * HW;
        const v2f a = *(const v2f*)(xp + pym + P);
        const v2f m = *(const v2f*)(xp + py0 + P);
        const v2f z = *(const v2f*)(xp + pyp + P);
        ctr0[c] = m.x; ctr1[c] = m.y;
        mxlo[c] = fmaxf(fmaxf(a.x, m.x), z.x);
        mxhi[c] = fmaxf(fmaxf(a.y, m.y), z.y);
        mnlo[c] = fminf(fminf(a.x, m.x), z.x);
        mnhi[c] = fminf(fminf(a.y, m.y), z.y);
    }

    float lmx[3], lmn[3], rmx[3], rmn[3];
    #pragma unroll
    for (int c = 0; c < Cn; ++c) {
        lmx[c] = __shfl_up(mxhi[c], 1);
        lmn[c] = __shfl_up(mnhi[c], 1);
        rmx[c] = __shfl_down(mxlo[c], 1);
        rmn[c] = __shfl_down(mnlo[c], 1);
    }

    if (lane == 0 || lane == 63) {
        const int ex = (lane == 0) ? max(P - 1, 0) : min(P + 2, Wn - 1);
        #pragma unroll
        for (int c = 0; c < Cn; ++c) {
            const float* __restrict__ xp = xin + (size_t)(b * Cn + c) * HW;
            const float e0 = xp[pym + ex];
            const float e1 = xp[py0 + ex];
            const float e2 = xp[pyp + ex];
            const float emax = fmaxf(fmaxf(e0, e1), e2);
            const float emin = fminf(fminf(e0, e1), e2);
            if (lane == 0) { lmx[c] = emax; lmn[c] = emin; }
            else           { rmx[c] = emax; rmn[c] = emin; }
        }
    }

    #pragma unroll
    for (int c = 0; c < Cn; ++c) {
        const float mx0 = fmaxf(fmaxf(lmx[c], mxlo[c]), mxhi[c]);
        const float mn0 = fminf(fminf(lmn[c], mnlo[c]), mnhi[c]);
        const float mx1 = fmaxf(fmaxf(mxlo[c], mxhi[c]), rmx[c]);
        const float mn1 = fminf(fminf(mnlo[c], mnhi[c]), rmn[c]);

        float rv0 = fminf(fmaxf(rep0[c], 0.0f), 1.0f);
        float rv1 = fminf(fmaxf(rep1[c], 0.0f), 1.0f);
        rv0 = fminf(fmaxf(rv0, mn0), mx0);
        rv1 = fminf(fmaxf(rv1, mn1), mx1);

        v2f o;
        o.x = kAlpha * ctr0[c] + (1.0f - kAlpha) * rv0;
        o.y = kAlpha * ctr1[c] + (1.0f - kAlpha) * rv1;
        __builtin_nontemporal_store(o, (v2f*)&out[(size_t)(b * Cn + c) * HW + p]);
    }
}

// ---- planar fallback (ws too small): 1 px/thread, 36 scalar gathers ----
__global__ __launch_bounds__(128)
void taa_fallback(const float* __restrict__ xin,
                  const v2f* __restrict__ mv,
                  const float* __restrict__ hist,
                  float* __restrict__ out)
{
    const int bid = blockIdx.x;
    const int b   = bid & 3;
    const int rr  = bid >> 2;
    const int py  = rr / 15;
    const int px  = (rr - py * 15) * 128 + threadIdx.x;
    const int p   = py * Wn + px;

    const v2f g = mv[(size_t)b * HW + p];
    const float posx = (g.x + 1.0f) * 0.5f * (float)Wn;
    const float posy = (g.y + 1.0f) * 0.5f * (float)Hn;
    const float Xf = floorf(posx - 0.5f);
    const float Yf = floorf(posy - 0.5f);
    const float fx = posx - (Xf + 0.5f);
    const float fy = posy - (Yf + 0.5f);
    const float fx2 = fx * fx, fx3 = fx2 * fx;
    const float w0x = -0.5f * fx3 + fx2 - 0.5f * fx;
    const float w1x =  1.5f * fx3 - 2.5f * fx2 + 1.0f;
    const float w2x = -1.5f * fx3 + 2.0f * fx2 + 0.5f * fx;
    const float w3x =  0.5f * fx3 - 0.5f * fx2;
    const float w12x = w1x + w2x, bxr = w2x / w12x;
    const float fy2 = fy * fy, fy3 = fy2 * fy;
    const float w0y = -0.5f * fy3 + fy2 - 0.5f * fy;
    const float w1y =  1.5f * fy3 - 2.5f * fy2 + 1.0f;
    const float w2y = -1.5f * fy3 + 2.0f * fy2 + 0.5f * fy;
    const float w3y =  0.5f * fy3 - 0.5f * fy2;
    const float w12y = w1y + w2y, byr = w2y / w12y;
    const int X = (int)Xf, Y = (int)Yf;
    const float vxm1 = ((unsigned)(X - 1) < (unsigned)Wn) ? 1.0f : 0.0f;
    const float vx0  = ((unsigned)(X    ) < (unsigned)Wn) ? 1.0f : 0.0f;
    const float vx1  = ((unsigned)(X + 1) < (unsigned)Wn) ? 1.0f : 0.0f;
    const float vx2  = ((unsigned)(X + 2) < (unsigned)Wn) ? 1.0f : 0.0f;
    const float vym1 = ((unsigned)(Y - 1) < (unsigned)Hn) ? 1.0f : 0.0f;
    const float vy0  = ((unsigned)(Y    ) < (unsigned)Hn) ? 1.0f : 0.0f;
    const float vy1  = ((unsigned)(Y + 1) < (unsigned)Hn) ? 1.0f : 0.0f;
    const float vy2  = ((unsigned)(Y + 2) < (unsigned)Hn) ? 1.0f : 0.0f;
    const float k1 = w12x * w0y, k2 = w0x * w12y, k3 = w3x * w12y;
    const float k4 = w12x * w3y, k5 = w12x * w12y;
    const float inv_denom = 1.0f / (k1 + k2 + k3 + k4 + k5);
    const float wxl = 1.0f - bxr, wxh = bxr, wyl = 1.0f - byr, wyh = byr;
    const float wA = k1 * wxl * (vym1 * vx0), wB = k1 * wxh * (vym1 * vx1);
    const float wC = k2 * wyl * (vxm1 * vy0), wD = k2 * wyh * (vxm1 * vy1);
    const float wE = k3 * wyl * (vx2 * vy0),  wF = k3 * wyh * (vx2 * vy1);
    const float wG = k4 * wxl * (vy2 * vx0),  wH = k4 * wxh * (vy2 * vx1);
    const float wI = k5 * wxl * wyl * (vx0 * vy0), wJ = k5 * wxh * wyl * (vx1 * vy0);
    const float wK = k5 * wxl * wyh * (vx0 * vy1), wL = k5 * wxh * wyh * (vx1 * vy1);
    const int cxm1 = min(max(X - 1, 0), Wn - 1), cx0 = min(max(X, 0), Wn - 1);
    const int cx1 = min(max(X + 1, 0), Wn - 1),  cx2 = min(max(X + 2, 0), Wn - 1);
    const int rym1 = min(max(Y - 1, 0), Hn - 1) * Wn, ry0 = min(max(Y, 0), Hn - 1) * Wn;
    const int ry1 = min(max(Y + 1, 0), Hn - 1) * Wn,  ry2 = min(max(Y + 2, 0), Hn - 1) * Wn;

    const int pym = max(py - 1, 0) * Wn;
    const int py0 = py * Wn;
    const int pyp = min(py + 1, Hn - 1) * Wn;
    const int pxm = max(px - 1, 0);
    const int pxp = min(px + 1, Wn - 1);

    #pragma unroll
    for (int c = 0; c < Cn; ++c) {
        const size_t plane = (size_t)(b * Cn + c) * HW;
        const float* __restrict__ hp = hist + plane;
        float acc = wA * hp[rym1 + cx0];
        acc = fmaf(wB, hp[rym1 + cx1], acc);
        acc = fmaf(wC, hp[ry0 + cxm1], acc);
        acc = fmaf(wD, hp[ry1 + cxm1], acc);
        acc = fmaf(wE, hp[ry0 + cx2], acc);
        acc = fmaf(wF, hp[ry1 + cx2], acc);
        acc = fmaf(wG, hp[ry2 + cx0], acc);
        acc = fmaf(wH, hp[ry2 + cx1], acc);
        acc = fmaf(wI, hp[ry0 + cx0], acc);
        acc = fmaf(wJ, hp[ry0 + cx1], acc);
        acc = fmaf(wK, hp[ry1 + cx0], acc);
        acc = fmaf(wL, hp[ry1 + cx1], acc);
        float rv = fminf(fmaxf(acc * inv_denom, 0.0f), 1.0f);

        const float* __restrict__ xp = xin + plane;
        const float r0a = xp[pym + pxm], r0b = xp[pym + px], r0c = xp[pym + pxp];
        const float r1a = xp[py0 + pxm], r1b = xp[py0 + px], r1c = xp[py0 + pxp];
        const float r2a = xp[pyp + pxm], r2b = xp[pyp + px], r2c = xp[pyp + pxp];
        const float mx = fmaxf(fmaxf(fmaxf(r0a, r0b), fmaxf(r0c, r1a)),
                               fmaxf(fmaxf(r1b, r1c), fmaxf(fmaxf(r2a, r2b), r2c)));
        const float mn = fminf(fminf(fminf(r0a, r0b), fminf(r0c, r1a)),
                               fminf(fminf(r1b, r1c), fminf(fminf(r2a, r2b), r2c)));
        rv = fminf(fmaxf(rv, mn), mx);
        out[plane + p] = kAlpha * r1b + (1.0f - kAlpha) * rv;
    }
}

} // namespace

extern "C" void kernel_launch(void* const* d_in, const int* in_sizes, int n_in,
                              void* d_out, int out_size, void* d_ws, size_t ws_size,
                              hipStream_t stream) {
    const float* x    = (const float*)d_in[0];
    const v2f*   mv   = (const v2f*)d_in[1];
    const float* hist = (const float*)d_in[2];
    float* outp = (float*)d_out;

    const size_t phased_bytes = (size_t)Bn * 4 * HW * 4;   // 132.7 MB
    const size_t packed_bytes = (size_t)Bn * HW * 4;       // 33.2 MB

    if (ws_size >= phased_bytes) {
        unsigned int* packed = (unsigned int*)d_ws;
        pack_phased<<<Bn * Hn * Gt / 256, 256, 0, stream>>>(hist, packed);
        taa_main4<<<Bn * HW / 256, 128, 0, stream>>>(x, mv, packed, outp);
    } else if (ws_size >= packed_bytes) {
        unsigned int* packed = (unsigned int*)d_ws;
        pack_tiled<<<Bn * Ht * 15, 128, 0, stream>>>(hist, packed);
        taa_main2<<<Bn * HW / 256, 128, 0, stream>>>(x, mv, packed, outp);
    } else {
        taa_fallback<<<(Wn / 128) * Hn * Bn, 128, 0, stream>>>(x, mv, hist, outp);
    }
}

// Round 3
// 419.842 us; speedup vs baseline: 1.4533x; 1.4533x over previous
//
#include <hip/hip_runtime.h>

namespace {

constexpr int Bn = 4, Cn = 3, Hn = 1080, Wn = 1920;
constexpr int HW = Hn * Wn;
constexpr float kAlpha = 0.1f;
constexpr float kInv2047 = 1.0f / 2047.0f;
constexpr float kInv1023 = 1.0f / 1023.0f;
constexpr int kPad = 16;            // dwords of front/back workspace padding

typedef float v2f __attribute__((ext_vector_type(2)));
typedef float v4f __attribute__((ext_vector_type(4)));
typedef unsigned int v4u __attribute__((ext_vector_type(4)));
// 4B-aligned vector loads: gfx9+ unaligned-access-mode keeps these single
// global_load_dwordx4/x2 instructions (line-crossing lanes split in HW).
typedef unsigned int v4u_u __attribute__((ext_vector_type(4), aligned(4)));
typedef unsigned int v2u_u __attribute__((ext_vector_type(2), aligned(4)));

__device__ inline unsigned quant_rgb(float r, float g, float b)
{
    const unsigned R  = (unsigned)(fminf(fmaxf(r, 0.0f), 1.0f) * 2047.0f + 0.5f);
    const unsigned G  = (unsigned)(fminf(fmaxf(g, 0.0f), 1.0f) * 2047.0f + 0.5f);
    const unsigned Bq = (unsigned)(fminf(fmaxf(b, 0.0f), 1.0f) * 1023.0f + 0.5f);
    return (R << 21) | (G << 10) | Bq;
}

// ---- pack planar RGB float -> R11G11B10 dwords, plain row-major ----
// Pure streaming: coalesced v4f reads, coalesced v4u writes.
__global__ __launch_bounds__(256)
void pack_linear(const float* __restrict__ hist, unsigned int* __restrict__ packed)
{
    const int tid = blockIdx.x * 256 + threadIdx.x;  // Bn*HW/4 threads
    const int b   = tid / (HW / 4);
    const int r   = tid - b * (HW / 4);

    const float* base = hist + (size_t)b * Cn * HW + (size_t)r * 4;
    const v4f rr = *(const v4f*)(base);
    const v4f gg = *(const v4f*)(base + HW);
    const v4f bb = *(const v4f*)(base + 2 * HW);

    v4u t;
    t.x = quant_rgb(rr.x, gg.x, bb.x);
    t.y = quant_rgb(rr.y, gg.y, bb.y);
    t.z = quant_rgb(rr.z, gg.z, bb.z);
    t.w = quant_rgb(rr.w, gg.w, bb.w);
    *(v4u*)(packed + (size_t)b * HW + (size_t)r * 4) = t;
}

// one pixel's 5-tap bicubic: 2 unaligned dwordx4 + 2 unaligned dwordx2,
// branch-free, direct vector-component taps (no sel4).
__device__ inline void bicubic_gather_lin(const unsigned int* __restrict__ pp,
                                          float gx, float gy, float rep[3])
{
    const float posx = (gx + 1.0f) * 0.5f * (float)Wn;
    const float posy = (gy + 1.0f) * 0.5f * (float)Hn;
    const float Xf = floorf(posx - 0.5f);
    const float Yf = floorf(posy - 0.5f);
    const float fx = posx - (Xf + 0.5f);
    const float fy = posy - (Yf + 0.5f);

    const float fx2 = fx * fx, fx3 = fx2 * fx;
    const float w0x = -0.5f * fx3 + fx2 - 0.5f * fx;
    const float w1x =  1.5f * fx3 - 2.5f * fx2 + 1.0f;
    const float w2x = -1.5f * fx3 + 2.0f * fx2 + 0.5f * fx;
    const float w3x =  0.5f * fx3 - 0.5f * fx2;
    const float w12x = w1x + w2x;
    const float bxr  = w2x / w12x;

    const float fy2 = fy * fy, fy3 = fy2 * fy;
    const float w0y = -0.5f * fy3 + fy2 - 0.5f * fy;
    const float w1y =  1.5f * fy3 - 2.5f * fy2 + 1.0f;
    const float w2y = -1.5f * fy3 + 2.0f * fy2 + 0.5f * fy;
    const float w3y =  0.5f * fy3 - 0.5f * fy2;
    const float w12y = w1y + w2y;
    const float byr  = w2y / w12y;

    const int X = (int)Xf;
    const int Y = (int)Yf;

    const float vxm1 = ((unsigned)(X - 1) < (unsigned)Wn) ? 1.0f : 0.0f;
    const float vx0  = ((unsigned)(X    ) < (unsigned)Wn) ? 1.0f : 0.0f;
    const float vx1  = ((unsigned)(X + 1) < (unsigned)Wn) ? 1.0f : 0.0f;
    const float vx2  = ((unsigned)(X + 2) < (unsigned)Wn) ? 1.0f : 0.0f;
    const float vym1 = ((unsigned)(Y - 1) < (unsigned)Hn) ? 1.0f : 0.0f;
    const float vy0  = ((unsigned)(Y    ) < (unsigned)Hn) ? 1.0f : 0.0f;
    const float vy1  = ((unsigned)(Y + 1) < (unsigned)Hn) ? 1.0f : 0.0f;
    const float vy2  = ((unsigned)(Y + 2) < (unsigned)Hn) ? 1.0f : 0.0f;

    const float k1 = w12x * w0y;
    const float k2 = w0x * w12y;
    const float k3 = w3x * w12y;
    const float k4 = w12x * w3y;
    const float k5 = w12x * w12y;
    const float inv_denom = 1.0f / (k1 + k2 + k3 + k4 + k5);

    const float wxl = 1.0f - bxr, wxh = bxr;
    const float wyl = 1.0f - byr, wyh = byr;

    const float wA = k1 * wxl * (vym1 * vx0);
    const float wB = k1 * wxh * (vym1 * vx1);
    const float wC = k2 * wyl * (vxm1 * vy0);
    const float wD = k2 * wyh * (vxm1 * vy1);
    const float wE = k3 * wyl * (vx2 * vy0);
    const float wF = k3 * wyh * (vx2 * vy1);
    const float wG = k4 * wxl * (vy2 * vx0);
    const float wH = k4 * wxh * (vy2 * vx1);
    const float wI = k5 * wxl * wyl * (vx0 * vy0);
    const float wJ = k5 * wxh * wyl * (vx1 * vy0);
    const float wK = k5 * wxl * wyh * (vx0 * vy1);
    const float wL = k5 * wxh * wyh * (vx1 * vy1);

    // rows (clamped) and columns: rows Y,Y+1 need cols X-1..X+2 (dwordx4 at
    // W0=X-1); rows Y-1,Y+2 need cols X..X+1 (dwordx2 at X). Out-of-range
    // columns carry zero weight; the workspace pads make the loads safe.
    const int W0  = X - 1;
    const int rYm = min(max(Y - 1, 0), Hn - 1) * Wn;
    const int rY0 = min(max(Y,     0), Hn - 1) * Wn;
    const int rY1 = min(max(Y + 1, 0), Hn - 1) * Wn;
    const int rY2 = min(max(Y + 2, 0), Hn - 1) * Wn;

    const v4u_u R0 = *(const v4u_u*)(pp + rY0 + W0);
    const v4u_u R1 = *(const v4u_u*)(pp + rY1 + W0);
    const v2u_u Rm = *(const v2u_u*)(pp + rYm + X);
    const v2u_u R2 = *(const v2u_u*)(pp + rY2 + X);

    float accR = 0.0f, accG = 0.0f, accB = 0.0f;
#define TAA_TAP(w_, t_) {                                                   \
    accR = fmaf(w_, (float)((t_) >> 21),           accR);                   \
    accG = fmaf(w_, (float)(((t_) >> 10) & 2047u), accG);                   \
    accB = fmaf(w_, (float)((t_) & 1023u),         accB); }
    // same accumulation order (A..L) as previous kernels for bit-stability
    TAA_TAP(wA, Rm.x) TAA_TAP(wB, Rm.y) TAA_TAP(wC, R0.x) TAA_TAP(wD, R1.x)
    TAA_TAP(wE, R0.w) TAA_TAP(wF, R1.w) TAA_TAP(wG, R2.x) TAA_TAP(wH, R2.y)
    TAA_TAP(wI, R0.y) TAA_TAP(wJ, R0.z) TAA_TAP(wK, R1.y) TAA_TAP(wL, R1.z)
#undef TAA_TAP
    rep[0] = accR * (kInv2047 * inv_denom);
    rep[1] = accG * (kInv2047 * inv_denom);
    rep[2] = accB * (kInv1023 * inv_denom);
}

// ---- main TAA kernel (row-major texture): 2 adjacent pixels per thread ----
__global__ __launch_bounds__(128)
void taa_main_lin(const float* __restrict__ xin,
                  const v2f* __restrict__ mv,
                  const unsigned int* __restrict__ packed,
                  float* __restrict__ out)
{
    // batch = bid & 3: round-robin block->XCD pins batch b to XCDs {b,b+4};
    // each XCD's L2 then holds that batch's ~2MB hot gather region.
    const int bid = blockIdx.x;            // 32400 blocks
    const int b   = bid & 3;
    const int r   = bid >> 2;              // 0..8099
    const int u   = r * 128 + threadIdx.x; // 2px-unit
    const int py  = u / 960;
    const int P   = (u - py * 960) * 2;    // even pixel
    const int p   = py * Wn + P;

    const v4f gg = __builtin_nontemporal_load((const v4f*)&mv[(size_t)b * HW + p]);

    const unsigned int* __restrict__ pp = packed + (size_t)b * HW;
    float rep0[3], rep1[3];
    bicubic_gather_lin(pp, gg.x, gg.y, rep0);
    bicubic_gather_lin(pp, gg.z, gg.w, rep1);

    // ---- 3x3 pool: float2 column loads + wave shuffles ----
    const int pym = max(py - 1, 0) * Wn;
    const int py0 = py * Wn;
    const int pyp = min(py + 1, Hn - 1) * Wn;
    const int lane = threadIdx.x & 63;

    float ctr0[3], ctr1[3];
    float mxlo[3], mxhi[3], mnlo[3], mnhi[3];
    #pragma unroll
    for (int c = 0; c < Cn; ++c) {
        const float* __restrict__ xp = xin + (size_t)(b * Cn + c) * HW;
        const v2f a = *(const v2f*)(xp + pym + P);
        const v2f m = *(const v2f*)(xp + py0 + P);
        const v2f z = *(const v2f*)(xp + pyp + P);
        ctr0[c] = m.x; ctr1[c] = m.y;
        mxlo[c] = fmaxf(fmaxf(a.x, m.x), z.x);
        mxhi[c] = fmaxf(fmaxf(a.y, m.y), z.y);
        mnlo[c] = fminf(fminf(a.x, m.x), z.x);
        mnhi[c] = fminf(fminf(a.y, m.y), z.y);
    }

    float lmx[3], lmn[3], rmx[3], rmn[3];   // left = col P-1, right = col P+2
    #pragma unroll
    for (int c = 0; c < Cn; ++c) {
        lmx[c] = __shfl_up(mxhi[c], 1);
        lmn[c] = __shfl_up(mnhi[c], 1);
        rmx[c] = __shfl_down(mxlo[c], 1);
        rmn[c] = __shfl_down(mnlo[c], 1);
    }

    // wave-edge lanes fetch their missing neighbor column directly
    if (lane == 0 || lane == 63) {
        const int ex = (lane == 0) ? max(P - 1, 0) : min(P + 2, Wn - 1);
        #pragma unroll
        for (int c = 0; c < Cn; ++c) {
            const float* __restrict__ xp = xin + (size_t)(b * Cn + c) * HW;
            const float e0 = xp[pym + ex];
            const float e1 = xp[py0 + ex];
            const float e2 = xp[pyp + ex];
            const float emax = fmaxf(fmaxf(e0, e1), e2);
            const float emin = fminf(fminf(e0, e1), e2);
            if (lane == 0) { lmx[c] = emax; lmn[c] = emin; }
            else           { rmx[c] = emax; rmn[c] = emin; }
        }
    }

    #pragma unroll
    for (int c = 0; c < Cn; ++c) {
        const float mx0 = fmaxf(fmaxf(lmx[c], mxlo[c]), mxhi[c]);
        const float mn0 = fminf(fminf(lmn[c], mnlo[c]), mnhi[c]);
        const float mx1 = fmaxf(fmaxf(mxlo[c], mxhi[c]), rmx[c]);
        const float mn1 = fminf(fminf(mnlo[c], mnhi[c]), rmn[c]);

        float rv0 = fminf(fmaxf(rep0[c], 0.0f), 1.0f);
        float rv1 = fminf(fmaxf(rep1[c], 0.0f), 1.0f);
        rv0 = fminf(fmaxf(rv0, mn0), mx0);
        rv1 = fminf(fmaxf(rv1, mn1), mx1);

        v2f o;
        o.x = kAlpha * ctr0[c] + (1.0f - kAlpha) * rv0;
        o.y = kAlpha * ctr1[c] + (1.0f - kAlpha) * rv1;
        __builtin_nontemporal_store(o, (v2f*)&out[(size_t)(b * Cn + c) * HW + p]);
    }
}

// ---- planar fallback (ws too small): 1 px/thread, 36 scalar gathers ----
__global__ __launch_bounds__(128)
void taa_fallback(const float* __restrict__ xin,
                  const v2f* __restrict__ mv,
                  const float* __restrict__ hist,
                  float* __restrict__ out)
{
    const int bid = blockIdx.x;
    const int b   = bid & 3;
    const int rr  = bid >> 2;
    const int py  = rr / 15;
    const int px  = (rr - py * 15) * 128 + threadIdx.x;
    const int p   = py * Wn + px;

    const v2f g = mv[(size_t)b * HW + p];
    const float posx = (g.x + 1.0f) * 0.5f * (float)Wn;
    const float posy = (g.y + 1.0f) * 0.5f * (float)Hn;
    const float Xf = floorf(posx - 0.5f);
    const float Yf = floorf(posy - 0.5f);
    const float fx = posx - (Xf + 0.5f);
    const float fy = posy - (Yf + 0.5f);
    const float fx2 = fx * fx, fx3 = fx2 * fx;
    const float w0x = -0.5f * fx3 + fx2 - 0.5f * fx;
    const float w1x =  1.5f * fx3 - 2.5f * fx2 + 1.0f;
    const float w2x = -1.5f * fx3 + 2.0f * fx2 + 0.5f * fx;
    const float w3x =  0.5f * fx3 - 0.5f * fx2;
    const float w12x = w1x + w2x, bxr = w2x / w12x;
    const float fy2 = fy * fy, fy3 = fy2 * fy;
    const float w0y = -0.5f * fy3 + fy2 - 0.5f * fy;
    const float w1y =  1.5f * fy3 - 2.5f * fy2 + 1.0f;
    const float w2y = -1.5f * fy3 + 2.0f * fy2 + 0.5f * fy;
    const float w3y =  0.5f * fy3 - 0.5f * fy2;
    const float w12y = w1y + w2y, byr = w2y / w12y;
    const int X = (int)Xf, Y = (int)Yf;
    const float vxm1 = ((unsigned)(X - 1) < (unsigned)Wn) ? 1.0f : 0.0f;
    const float vx0  = ((unsigned)(X    ) < (unsigned)Wn) ? 1.0f : 0.0f;
    const float vx1  = ((unsigned)(X + 1) < (unsigned)Wn) ? 1.0f : 0.0f;
    const float vx2  = ((unsigned)(X + 2) < (unsigned)Wn) ? 1.0f : 0.0f;
    const float vym1 = ((unsigned)(Y - 1) < (unsigned)Hn) ? 1.0f : 0.0f;
    const float vy0  = ((unsigned)(Y    ) < (unsigned)Hn) ? 1.0f : 0.0f;
    const float vy1  = ((unsigned)(Y + 1) < (unsigned)Hn) ? 1.0f : 0.0f;
    const float vy2  = ((unsigned)(Y + 2) < (unsigned)Hn) ? 1.0f : 0.0f;
    const float k1 = w12x * w0y, k2 = w0x * w12y, k3 = w3x * w12y;
    const float k4 = w12x * w3y, k5 = w12x * w12y;
    const float inv_denom = 1.0f / (k1 + k2 + k3 + k4 + k5);
    const float wxl = 1.0f - bxr, wxh = bxr, wyl = 1.0f - byr, wyh = byr;
    const float wA = k1 * wxl * (vym1 * vx0), wB = k1 * wxh * (vym1 * vx1);
    const float wC = k2 * wyl * (vxm1 * vy0), wD = k2 * wyh * (vxm1 * vy1);
    const float wE = k3 * wyl * (vx2 * vy0),  wF = k3 * wyh * (vx2 * vy1);
    const float wG = k4 * wxl * (vy2 * vx0),  wH = k4 * wxh * (vy2 * vx1);
    const float wI = k5 * wxl * wyl * (vx0 * vy0), wJ = k5 * wxh * wyl * (vx1 * vy0);
    const float wK = k5 * wxl * wyh * (vx0 * vy1), wL = k5 * wxh * wyh * (vx1 * vy1);
    const int cxm1 = min(max(X - 1, 0), Wn - 1), cx0 = min(max(X, 0), Wn - 1);
    const int cx1 = min(max(X + 1, 0), Wn - 1),  cx2 = min(max(X + 2, 0), Wn - 1);
    const int rym1 = min(max(Y - 1, 0), Hn - 1) * Wn, ry0 = min(max(Y, 0), Hn - 1) * Wn;
    const int ry1 = min(max(Y + 1, 0), Hn - 1) * Wn,  ry2 = min(max(Y + 2, 0), Hn - 1) * Wn;

    const int pym = max(py - 1, 0) * Wn;
    const int py0 = py * Wn;
    const int pyp = min(py + 1, Hn - 1) * Wn;
    const int pxm = max(px - 1, 0);
    const int pxp = min(px + 1, Wn - 1);

    #pragma unroll
    for (int c = 0; c < Cn; ++c) {
        const size_t plane = (size_t)(b * Cn + c) * HW;
        const float* __restrict__ hp = hist + plane;
        float acc = wA * hp[rym1 + cx0];
        acc = fmaf(wB, hp[rym1 + cx1], acc);
        acc = fmaf(wC, hp[ry0 + cxm1], acc);
        acc = fmaf(wD, hp[ry1 + cxm1], acc);
        acc = fmaf(wE, hp[ry0 + cx2], acc);
        acc = fmaf(wF, hp[ry1 + cx2], acc);
        acc = fmaf(wG, hp[ry2 + cx0], acc);
        acc = fmaf(wH, hp[ry2 + cx1], acc);
        acc = fmaf(wI, hp[ry0 + cx0], acc);
        acc = fmaf(wJ, hp[ry0 + cx1], acc);
        acc = fmaf(wK, hp[ry1 + cx0], acc);
        acc = fmaf(wL, hp[ry1 + cx1], acc);
        float rv = fminf(fmaxf(acc * inv_denom, 0.0f), 1.0f);

        const float* __restrict__ xp = xin + plane;
        const float r0a = xp[pym + pxm], r0b = xp[pym + px], r0c = xp[pym + pxp];
        const float r1a = xp[py0 + pxm], r1b = xp[py0 + px], r1c = xp[py0 + pxp];
        const float r2a = xp[pyp + pxm], r2b = xp[pyp + px], r2c = xp[pyp + pxp];
        const float mx = fmaxf(fmaxf(fmaxf(r0a, r0b), fmaxf(r0c, r1a)),
                               fmaxf(fmaxf(r1b, r1c), fmaxf(fmaxf(r2a, r2b), r2c)));
        const float mn = fminf(fminf(fminf(r0a, r0b), fminf(r0c, r1a)),
                               fminf(fminf(r1b, r1c), fminf(fminf(r2a, r2b), r2c)));
        rv = fminf(fmaxf(rv, mn), mx);
        out[plane + p] = kAlpha * r1b + (1.0f - kAlpha) * rv;
    }
}

} // namespace

extern "C" void kernel_launch(void* const* d_in, const int* in_sizes, int n_in,
                              void* d_out, int out_size, void* d_ws, size_t ws_size,
                              hipStream_t stream) {
    const float* x    = (const float*)d_in[0];
    const v2f*   mv   = (const v2f*)d_in[1];
    const float* hist = (const float*)d_in[2];
    float* outp = (float*)d_out;

    const size_t lin_bytes = ((size_t)Bn * HW + 2 * kPad) * 4;   // ~33.2 MB

    if (ws_size >= lin_bytes) {
        unsigned int* packed = (unsigned int*)d_ws + kPad;  // front pad for X-1<0
        pack_linear<<<Bn * HW / 4 / 256, 256, 0, stream>>>(hist, packed);
        taa_main_lin<<<Bn * HW / 256, 128, 0, stream>>>(x, mv, packed, outp);
    } else {
        taa_fallback<<<(Wn / 128) * Hn * Bn, 128, 0, stream>>>(x, mv, hist, outp);
    }
}

// Round 4
// 406.769 us; speedup vs baseline: 1.5000x; 1.0321x over previous
//
#include <hip/hip_runtime.h>

namespace {

constexpr int Bn = 4, Cn = 3, Hn = 1080, Wn = 1920;
constexpr int HW = Hn * Wn;
constexpr int Qn = Hn / 2;                       // 540 pair-rows
constexpr int PRSTRIDE = (Qn + 1) * Wn * 2;      // per-batch dwords incl. pad pair-row
constexpr float kAlpha = 0.1f;
constexpr float kInv2047 = 1.0f / 2047.0f;
constexpr float kInv1023 = 1.0f / 1023.0f;
constexpr int kPad = 16;                         // dwords of front/back ws padding

typedef float v2f __attribute__((ext_vector_type(2)));
typedef float v4f __attribute__((ext_vector_type(4)));
typedef unsigned int v4u __attribute__((ext_vector_type(4)));
// 8B-aligned dwordx4 loads (pair entries are 8B): single instruction on gfx9+.
typedef unsigned int v4u_u __attribute__((ext_vector_type(4), aligned(8)));

__device__ inline unsigned quant_rgb(float r, float g, float b)
{
    const unsigned R  = (unsigned)(fminf(fmaxf(r, 0.0f), 1.0f) * 2047.0f + 0.5f);
    const unsigned G  = (unsigned)(fminf(fmaxf(g, 0.0f), 1.0f) * 2047.0f + 0.5f);
    const unsigned Bq = (unsigned)(fminf(fmaxf(b, 0.0f), 1.0f) * 1023.0f + 0.5f);
    return (R << 21) | (G << 10) | Bq;
}

// ---- pack planar RGB float -> R11G11B10, interleaved row-pair layout ----
// entry(q,x) = {quant(row 2q, x), quant(row 2q+1, x)} at dword offset (q*Wn+x)*2.
// Pure streaming: coalesced v4f reads of two rows, contiguous 32B writes.
__global__ __launch_bounds__(256)
void pack_pairs(const float* __restrict__ hist, unsigned int* __restrict__ packed)
{
    const int tid = blockIdx.x * 256 + threadIdx.x;  // Bn*Qn*480 threads
    const int g   = tid % (Wn / 4);
    const int rem = tid / (Wn / 4);
    const int q   = rem % Qn;
    const int b   = rem / Qn;
    const int x0  = g * 4;

    const float* base = hist + (size_t)b * Cn * HW + (size_t)(2 * q) * Wn + x0;
    const v4f r0 = *(const v4f*)(base);
    const v4f g0 = *(const v4f*)(base + HW);
    const v4f b0 = *(const v4f*)(base + 2 * HW);
    const v4f r1 = *(const v4f*)(base + Wn);
    const v4f g1 = *(const v4f*)(base + Wn + HW);
    const v4f b1 = *(const v4f*)(base + Wn + 2 * HW);

    v4u lo, hi;
    #pragma unroll
    for (int i = 0; i < 4; ++i) {
        lo[i] = quant_rgb(r0[i], g0[i], b0[i]);
        hi[i] = quant_rgb(r1[i], g1[i], b1[i]);
    }
    unsigned int* dst = packed + (size_t)b * PRSTRIDE + ((size_t)q * Wn + x0) * 2;
    *(v4u*)(dst)     = (v4u){lo.x, hi.x, lo.y, hi.y};
    *(v4u*)(dst + 4) = (v4u){lo.z, hi.z, lo.w, hi.w};
}

// one pixel's 5-tap bicubic from the pair texture: 4x dwordx4 (8B-aligned),
// ~3.2 scattered lines/px, parity-select extraction (branch-free).
__device__ inline void bicubic_gather_pair(const unsigned int* __restrict__ pp,
                                           float gx, float gy, float rep[3])
{
    const float posx = (gx + 1.0f) * 0.5f * (float)Wn;
    const float posy = (gy + 1.0f) * 0.5f * (float)Hn;
    const float Xf = floorf(posx - 0.5f);
    const float Yf = floorf(posy - 0.5f);
    const float fx = posx - (Xf + 0.5f);
    const float fy = posy - (Yf + 0.5f);

    const float fx2 = fx * fx, fx3 = fx2 * fx;
    const float w0x = -0.5f * fx3 + fx2 - 0.5f * fx;
    const float w1x =  1.5f * fx3 - 2.5f * fx2 + 1.0f;
    const float w2x = -1.5f * fx3 + 2.0f * fx2 + 0.5f * fx;
    const float w3x =  0.5f * fx3 - 0.5f * fx2;
    const float w12x = w1x + w2x;
    const float bxr  = w2x / w12x;

    const float fy2 = fy * fy, fy3 = fy2 * fy;
    const float w0y = -0.5f * fy3 + fy2 - 0.5f * fy;
    const float w1y =  1.5f * fy3 - 2.5f * fy2 + 1.0f;
    const float w2y = -1.5f * fy3 + 2.0f * fy2 + 0.5f * fy;
    const float w3y =  0.5f * fy3 - 0.5f * fy2;
    const float w12y = w1y + w2y;
    const float byr  = w2y / w12y;

    const int X = (int)Xf;
    const int Y = (int)Yf;

    const float vxm1 = ((unsigned)(X - 1) < (unsigned)Wn) ? 1.0f : 0.0f;
    const float vx0  = ((unsigned)(X    ) < (unsigned)Wn) ? 1.0f : 0.0f;
    const float vx1  = ((unsigned)(X + 1) < (unsigned)Wn) ? 1.0f : 0.0f;
    const float vx2  = ((unsigned)(X + 2) < (unsigned)Wn) ? 1.0f : 0.0f;
    const float vym1 = ((unsigned)(Y - 1) < (unsigned)Hn) ? 1.0f : 0.0f;
    const float vy0  = ((unsigned)(Y    ) < (unsigned)Hn) ? 1.0f : 0.0f;
    const float vy1  = ((unsigned)(Y + 1) < (unsigned)Hn) ? 1.0f : 0.0f;
    const float vy2  = ((unsigned)(Y + 2) < (unsigned)Hn) ? 1.0f : 0.0f;

    const float k1 = w12x * w0y;
    const float k2 = w0x * w12y;
    const float k3 = w3x * w12y;
    const float k4 = w12x * w3y;
    const float k5 = w12x * w12y;
    const float inv_denom = 1.0f / (k1 + k2 + k3 + k4 + k5);

    const float wxl = 1.0f - bxr, wxh = bxr;
    const float wyl = 1.0f - byr, wyh = byr;

    const float wA = k1 * wxl * (vym1 * vx0);
    const float wB = k1 * wxh * (vym1 * vx1);
    const float wC = k2 * wyl * (vxm1 * vy0);
    const float wD = k2 * wyh * (vxm1 * vy1);
    const float wE = k3 * wyl * (vx2 * vy0);
    const float wF = k3 * wyh * (vx2 * vy1);
    const float wG = k4 * wxl * (vy2 * vx0);
    const float wH = k4 * wxh * (vy2 * vx1);
    const float wI = k5 * wxl * wyl * (vx0 * vy0);
    const float wJ = k5 * wxh * wyl * (vx1 * vy0);
    const float wK = k5 * wxl * wyh * (vx0 * vy1);
    const float wL = k5 * wxh * wyh * (vx1 * vy1);

    // pair-row indices. Y odd: pair q = rows {Y-1,Y}, pair q+1 = {Y+1,Y+2}.
    // Y even: pair q = {Y,Y+1}, pair q-1 upper = Y-1, pair q+1 lower = Y+2.
    // Clamped pair indices only ever serve zero-weight rows (incl. pad row Qn).
    const int q   = Y >> 1;                    // arithmetic shift: floor div
    const int par = Y & 1;
    const int qA  = min(max(q,     0), Qn);
    const int qB  = min(max(q + 1, 0), Qn);
    const int qC  = min(max(q - 1, 0), Qn);

    const int eA  = (qA * Wn + (X - 1)) * 2;
    const int eL2 = par ? (qB * Wn + (X - 1)) * 2 : (qC * Wn + X) * 2;
    const int eL3 = par ? (qB * Wn + (X + 1)) * 2 : (qB * Wn + X) * 2;

    const v4u_u A0 = *(const v4u_u*)(pp + eA);       // pair qA, cols X-1,X
    const v4u_u A1 = *(const v4u_u*)(pp + eA + 4);   // pair qA, cols X+1,X+2
    const v4u_u L2 = *(const v4u_u*)(pp + eL2);
    const v4u_u L3 = *(const v4u_u*)(pp + eL3);

    const bool od = (par != 0);
    const unsigned tA = od ? A0.z : L2.y;
    const unsigned tB = od ? A1.x : L2.w;
    const unsigned tC = od ? A0.y : A0.x;
    const unsigned tD = od ? L2.x : A0.y;
    const unsigned tE = od ? A1.w : A1.z;
    const unsigned tF = od ? L3.z : A1.w;
    const unsigned tG = od ? L2.w : L3.x;
    const unsigned tH = od ? L3.y : L3.z;
    const unsigned tI = od ? A0.w : A0.z;
    const unsigned tJ = od ? A1.y : A1.x;
    const unsigned tK = od ? L2.z : A0.w;
    const unsigned tL = od ? L3.x : A1.y;

    float accR = 0.0f, accG = 0.0f, accB = 0.0f;
#define TAA_TAP(w_, t_) {                                                   \
    accR = fmaf(w_, (float)((t_) >> 21),           accR);                   \
    accG = fmaf(w_, (float)(((t_) >> 10) & 2047u), accG);                   \
    accB = fmaf(w_, (float)((t_) & 1023u),         accB); }
    // same accumulation order (A..L) as previous kernels for bit-stability
    TAA_TAP(wA, tA) TAA_TAP(wB, tB) TAA_TAP(wC, tC) TAA_TAP(wD, tD)
    TAA_TAP(wE, tE) TAA_TAP(wF, tF) TAA_TAP(wG, tG) TAA_TAP(wH, tH)
    TAA_TAP(wI, tI) TAA_TAP(wJ, tJ) TAA_TAP(wK, tK) TAA_TAP(wL, tL)
#undef TAA_TAP
    rep[0] = accR * (kInv2047 * inv_denom);
    rep[1] = accG * (kInv2047 * inv_denom);
    rep[2] = accB * (kInv1023 * inv_denom);
}

// ---- main TAA kernel (pair texture): 2 adjacent pixels per thread ----
__global__ __launch_bounds__(128)
void taa_main_pair(const float* __restrict__ xin,
                   const v2f* __restrict__ mv,
                   const unsigned int* __restrict__ packed,
                   float* __restrict__ out)
{
    // batch = bid & 3: round-robin block->XCD pins batch b to XCDs {b,b+4};
    // each XCD's L2 then holds that batch's ~2MB hot gather region.
    const int bid = blockIdx.x;            // 32400 blocks
    const int b   = bid & 3;
    const int r   = bid >> 2;              // 0..8099
    const int u   = r * 128 + threadIdx.x; // 2px-unit
    const int py  = u / 960;
    const int P   = (u - py * 960) * 2;    // even pixel
    const int p   = py * Wn + P;

    const v4f gg = __builtin_nontemporal_load((const v4f*)&mv[(size_t)b * HW + p]);

    const unsigned int* __restrict__ pp = packed + (size_t)b * PRSTRIDE;
    float rep0[3], rep1[3];
    bicubic_gather_pair(pp, gg.x, gg.y, rep0);
    bicubic_gather_pair(pp, gg.z, gg.w, rep1);

    // ---- 3x3 pool: float2 column loads + wave shuffles ----
    const int pym = max(py - 1, 0) * Wn;
    const int py0 = py * Wn;
    const int pyp = min(py + 1, Hn - 1) * Wn;
    const int lane = threadIdx.x & 63;

    float ctr0[3], ctr1[3];
    float mxlo[3], mxhi[3], mnlo[3], mnhi[3];
    #pragma unroll
    for (int c = 0; c < Cn; ++c) {
        const float* __restrict__ xp = xin + (size_t)(b * Cn + c) * HW;
        const v2f a = *(const v2f*)(xp + pym + P);
        const v2f m = *(const v2f*)(xp + py0 + P);
        const v2f z = *(const v2f*)(xp + pyp + P);
        ctr0[c] = m.x; ctr1[c] = m.y;
        mxlo[c] = fmaxf(fmaxf(a.x, m.x), z.x);
        mxhi[c] = fmaxf(fmaxf(a.y, m.y), z.y);
        mnlo[c] = fminf(fminf(a.x, m.x), z.x);
        mnhi[c] = fminf(fminf(a.y, m.y), z.y);
    }

    float lmx[3], lmn[3], rmx[3], rmn[3];   // left = col P-1, right = col P+2
    #pragma unroll
    for (int c = 0; c < Cn; ++c) {
        lmx[c] = __shfl_up(mxhi[c], 1);
        lmn[c] = __shfl_up(mnhi[c], 1);
        rmx[c] = __shfl_down(mxlo[c], 1);
        rmn[c] = __shfl_down(mnlo[c], 1);
    }

    // wave-edge lanes fetch their missing neighbor column directly
    if (lane == 0 || lane == 63) {
        const int ex = (lane == 0) ? max(P - 1, 0) : min(P + 2, Wn - 1);
        #pragma unroll
        for (int c = 0; c < Cn; ++c) {
            const float* __restrict__ xp = xin + (size_t)(b * Cn + c) * HW;
            const float e0 = xp[pym + ex];
            const float e1 = xp[py0 + ex];
            const float e2 = xp[pyp + ex];
            const float emax = fmaxf(fmaxf(e0, e1), e2);
            const float emin = fminf(fminf(e0, e1), e2);
            if (lane == 0) { lmx[c] = emax; lmn[c] = emin; }
            else           { rmx[c] = emax; rmn[c] = emin; }
        }
    }

    #pragma unroll
    for (int c = 0; c < Cn; ++c) {
        const float mx0 = fmaxf(fmaxf(lmx[c], mxlo[c]), mxhi[c]);
        const float mn0 = fminf(fminf(lmn[c], mnlo[c]), mnhi[c]);
        const float mx1 = fmaxf(fmaxf(mxlo[c], mxhi[c]), rmx[c]);
        const float mn1 = fminf(fminf(mnlo[c], mnhi[c]), rmn[c]);

        float rv0 = fminf(fmaxf(rep0[c], 0.0f), 1.0f);
        float rv1 = fminf(fmaxf(rep1[c], 0.0f), 1.0f);
        rv0 = fminf(fmaxf(rv0, mn0), mx0);
        rv1 = fminf(fmaxf(rv1, mn1), mx1);

        v2f o;
        o.x = kAlpha * ctr0[c] + (1.0f - kAlpha) * rv0;
        o.y = kAlpha * ctr1[c] + (1.0f - kAlpha) * rv1;
        __builtin_nontemporal_store(o, (v2f*)&out[(size_t)(b * Cn + c) * HW + p]);
    }
}

// ---- planar fallback (ws too small): 1 px/thread, 36 scalar gathers ----
__global__ __launch_bounds__(128)
void taa_fallback(const float* __restrict__ xin,
                  const v2f* __restrict__ mv,
                  const float* __restrict__ hist,
                  float* __restrict__ out)
{
    const int bid = blockIdx.x;
    const int b   = bid & 3;
    const int rr  = bid >> 2;
    const int py  = rr / 15;
    const int px  = (rr - py * 15) * 128 + threadIdx.x;
    const int p   = py * Wn + px;

    const v2f g = mv[(size_t)b * HW + p];
    const float posx = (g.x + 1.0f) * 0.5f * (float)Wn;
    const float posy = (g.y + 1.0f) * 0.5f * (float)Hn;
    const float Xf = floorf(posx - 0.5f);
    const float Yf = floorf(posy - 0.5f);
    const float fx = posx - (Xf + 0.5f);
    const float fy = posy - (Yf + 0.5f);
    const float fx2 = fx * fx, fx3 = fx2 * fx;
    const float w0x = -0.5f * fx3 + fx2 - 0.5f * fx;
    const float w1x =  1.5f * fx3 - 2.5f * fx2 + 1.0f;
    const float w2x = -1.5f * fx3 + 2.0f * fx2 + 0.5f * fx;
    const float w3x =  0.5f * fx3 - 0.5f * fx2;
    const float w12x = w1x + w2x, bxr = w2x / w12x;
    const float fy2 = fy * fy, fy3 = fy2 * fy;
    const float w0y = -0.5f * fy3 + fy2 - 0.5f * fy;
    const float w1y =  1.5f * fy3 - 2.5f * fy2 + 1.0f;
    const float w2y = -1.5f * fy3 + 2.0f * fy2 + 0.5f * fy;
    const float w3y =  0.5f * fy3 - 0.5f * fy2;
    const float w12y = w1y + w2y, byr = w2y / w12y;
    const int X = (int)Xf, Y = (int)Yf;
    const float vxm1 = ((unsigned)(X - 1) < (unsigned)Wn) ? 1.0f : 0.0f;
    const float vx0  = ((unsigned)(X    ) < (unsigned)Wn) ? 1.0f : 0.0f;
    const float vx1  = ((unsigned)(X + 1) < (unsigned)Wn) ? 1.0f : 0.0f;
    const float vx2  = ((unsigned)(X + 2) < (unsigned)Wn) ? 1.0f : 0.0f;
    const float vym1 = ((unsigned)(Y - 1) < (unsigned)Hn) ? 1.0f : 0.0f;
    const float vy0  = ((unsigned)(Y    ) < (unsigned)Hn) ? 1.0f : 0.0f;
    const float vy1  = ((unsigned)(Y + 1) < (unsigned)Hn) ? 1.0f : 0.0f;
    const float vy2  = ((unsigned)(Y + 2) < (unsigned)Hn) ? 1.0f : 0.0f;
    const float k1 = w12x * w0y, k2 = w0x * w12y, k3 = w3x * w12y;
    const float k4 = w12x * w3y, k5 = w12x * w12y;
    const float inv_denom = 1.0f / (k1 + k2 + k3 + k4 + k5);
    const float wxl = 1.0f - bxr, wxh = bxr, wyl = 1.0f - byr, wyh = byr;
    const float wA = k1 * wxl * (vym1 * vx0), wB = k1 * wxh * (vym1 * vx1);
    const float wC = k2 * wyl * (vxm1 * vy0), wD = k2 * wyh * (vxm1 * vy1);
    const float wE = k3 * wyl * (vx2 * vy0),  wF = k3 * wyh * (vx2 * vy1);
    const float wG = k4 * wxl * (vy2 * vx0),  wH = k4 * wxh * (vy2 * vx1);
    const float wI = k5 * wxl * wyl * (vx0 * vy0), wJ = k5 * wxh * wyl * (vx1 * vy0);
    const float wK = k5 * wxl * wyh * (vx0 * vy1), wL = k5 * wxh * wyh * (vx1 * vy1);
    const int cxm1 = min(max(X - 1, 0), Wn - 1), cx0 = min(max(X, 0), Wn - 1);
    const int cx1 = min(max(X + 1, 0), Wn - 1),  cx2 = min(max(X + 2, 0), Wn - 1);
    const int rym1 = min(max(Y - 1, 0), Hn - 1) * Wn, ry0 = min(max(Y, 0), Hn - 1) * Wn;
    const int ry1 = min(max(Y + 1, 0), Hn - 1) * Wn,  ry2 = min(max(Y + 2, 0), Hn - 1) * Wn;

    const int pym = max(py - 1, 0) * Wn;
    const int py0 = py * Wn;
    const int pyp = min(py + 1, Hn - 1) * Wn;
    const int pxm = max(px - 1, 0);
    const int pxp = min(px + 1, Wn - 1);

    #pragma unroll
    for (int c = 0; c < Cn; ++c) {
        const size_t plane = (size_t)(b * Cn + c) * HW;
        const float* __restrict__ hp = hist + plane;
        float acc = wA * hp[rym1 + cx0];
        acc = fmaf(wB, hp[rym1 + cx1], acc);
        acc = fmaf(wC, hp[ry0 + cxm1], acc);
        acc = fmaf(wD, hp[ry1 + cxm1], acc);
        acc = fmaf(wE, hp[ry0 + cx2], acc);
        acc = fmaf(wF, hp[ry1 + cx2], acc);
        acc = fmaf(wG, hp[ry2 + cx0], acc);
        acc = fmaf(wH, hp[ry2 + cx1], acc);
        acc = fmaf(wI, hp[ry0 + cx0], acc);
        acc = fmaf(wJ, hp[ry0 + cx1], acc);
        acc = fmaf(wK, hp[ry1 + cx0], acc);
        acc = fmaf(wL, hp[ry1 + cx1], acc);
        float rv = fminf(fmaxf(acc * inv_denom, 0.0f), 1.0f);

        const float* __restrict__ xp = xin + plane;
        const float r0a = xp[pym + pxm], r0b = xp[pym + px], r0c = xp[pym + pxp];
        const float r1a = xp[py0 + pxm], r1b = xp[py0 + px], r1c = xp[py0 + pxp];
        const float r2a = xp[pyp + pxm], r2b = xp[pyp + px], r2c = xp[pyp + pxp];
        const float mx = fmaxf(fmaxf(fmaxf(r0a, r0b), fmaxf(r0c, r1a)),
                               fmaxf(fmaxf(r1b, r1c), fmaxf(fmaxf(r2a, r2b), r2c)));
        const float mn = fminf(fminf(fminf(r0a, r0b), fminf(r0c, r1a)),
                               fminf(fminf(r1b, r1c), fminf(fminf(r2a, r2b), r2c)));
        rv = fminf(fmaxf(rv, mn), mx);
        out[plane + p] = kAlpha * r1b + (1.0f - kAlpha) * rv;
    }
}

} // namespace

extern "C" void kernel_launch(void* const* d_in, const int* in_sizes, int n_in,
                              void* d_out, int out_size, void* d_ws, size_t ws_size,
                              hipStream_t stream) {
    const float* x    = (const float*)d_in[0];
    const v2f*   mv   = (const v2f*)d_in[1];
    const float* hist = (const float*)d_in[2];
    float* outp = (float*)d_out;

    const size_t pair_bytes = ((size_t)Bn * PRSTRIDE + 2 * kPad) * 4;  // ~33.3 MB

    if (ws_size >= pair_bytes) {
        unsigned int* packed = (unsigned int*)d_ws + kPad;  // front pad for X-1<0
        pack_pairs<<<Bn * Qn * (Wn / 4) / 256, 256, 0, stream>>>(hist, packed);
        taa_main_pair<<<Bn * HW / 256, 128, 0, stream>>>(x, mv, packed, outp);
    } else {
        taa_fallback<<<(Wn / 128) * Hn * Bn, 128, 0, stream>>>(x, mv, hist, outp);
    }
}